// Round 19
// baseline (412.586 us; speedup 1.0000x reference)
//
#include <hip/hip_runtime.h>
#include <hip/hip_bf16.h>

constexpr int N_NODES    = 500000;
constexpr int N_EDGES    = 8000000;
constexpr int NUM_GRAPHS = 512;

constexpr int BSHIFT = 11;                              // 2048 nodes / coarse bucket
constexpr int BSIZE  = 1 << BSHIFT;
constexpr int NBKT   = (N_NODES + BSIZE - 1) / BSIZE;   // 245
constexpr int EPB    = 4096;                            // edges per block (pass A)
constexpr int NBLK_A = (N_EDGES + EPB - 1) / EPB;       // 1954
constexpr int NH     = NBKT * NBLK_A;                   // 478,730
constexpr int SCAN_B = 256;
constexpr int NSB    = (NH + SCAN_B - 1) / SCAN_B;      // 1871
constexpr int TSH    = 16;                              // src-tile = 65536 nodes
constexpr int CAP    = 20480;                           // LDS sout capacity

// ---- bf16 helpers (bit-level, RNE pack) ----
__device__ __forceinline__ float bf_lo(unsigned u) { return __uint_as_float(u << 16); }
__device__ __forceinline__ float bf_hi(unsigned u) { return __uint_as_float(u & 0xFFFF0000u); }
__device__ __forceinline__ unsigned short f2bf(float f) {
  unsigned u = __float_as_uint(f);
  return (unsigned short)((u + 0x7FFFu + ((u >> 16) & 1u)) >> 16);
}
__device__ __forceinline__ unsigned packbf(float a, float b) {
  return (unsigned)f2bf(a) | ((unsigned)f2bf(b) << 16);
}

// ---- fp8 e4m3fn helpers (values >= 0 only; sign elided) ----
__device__ __forceinline__ unsigned f2e4m3(float x) {
  x = fminf(x, 448.0f);
  unsigned xb = __float_as_uint(x);
  int e = (int)(xb >> 23) - 127;
  if (e < -6) {                               // denormal grid: step 2^-9
    int m = (int)rintf(x * 512.0f);           // 0..8
    return (m <= 7) ? (unsigned)m : 0x08u;    // 8 -> smallest normal 2^-6
  }
  unsigned lsb = (xb >> 20) & 1;
  unsigned r = xb + 0x7FFFFu + lsb;           // RNE into 3-bit mantissa (carry-safe)
  int e2 = (int)(r >> 23) - 127;
  unsigned m3 = (r >> 20) & 7;
  return (unsigned)(((e2 + 7) << 3) | m3);
}
__device__ __forceinline__ float e4m3f(unsigned b) {
  unsigned e = (b >> 3) & 0xF, m = b & 7;
  float norm = __uint_as_float(((e + 120u) << 23) | (m << 20));
  float den = (float)m * 0.001953125f;        // m * 2^-9
  return e ? norm : den;
}

// ---- pass A1: per-block coarse histogram (LDS atomics only) ----
__global__ void k_hist(const int* __restrict__ dst, int* __restrict__ H) {
  __shared__ int h[NBKT];
  for (int i = threadIdx.x; i < NBKT; i += blockDim.x) h[i] = 0;
  __syncthreads();
  int e0 = blockIdx.x * EPB;
  int e1 = min(e0 + EPB, N_EDGES);
  for (int e = e0 + threadIdx.x; e < e1; e += blockDim.x)
    atomicAdd(&h[dst[e] >> BSHIFT], 1);
  __syncthreads();
  for (int i = threadIdx.x; i < NBKT; i += blockDim.x)
    H[i * NBLK_A + blockIdx.x] = h[i];                  // bucket-major
}

// ---- exclusive scan of H: 2 kernels (scan3 folded into consumers) ----
__global__ void k_scan1(const int* __restrict__ in, int* __restrict__ out,
                        int* __restrict__ bsum, int n) {
  __shared__ int tmp[SCAN_B];
  int t = threadIdx.x;
  int i = blockIdx.x * SCAN_B + t;
  int v = (i < n) ? in[i] : 0;
  tmp[t] = v;
  __syncthreads();
  for (int off = 1; off < SCAN_B; off <<= 1) {
    int a = (t >= off) ? tmp[t - off] : 0;
    __syncthreads();
    tmp[t] += a;
    __syncthreads();
  }
  if (i < n) out[i] = tmp[t] - v;
  if (t == SCAN_B - 1) bsum[blockIdx.x] = tmp[t];
}

__global__ void k_scan2(int* __restrict__ bsum, int nb) {  // in-place exclusive
  __shared__ int tmp[SCAN_B];
  int t = threadIdx.x;
  int carry = 0;
  for (int base = 0; base < nb; base += SCAN_B) {
    int i = base + t;
    int v = (i < nb) ? bsum[i] : 0;
    tmp[t] = v;
    __syncthreads();
    for (int off = 1; off < SCAN_B; off <<= 1) {
      int a = (t >= off) ? tmp[t - off] : 0;
      __syncthreads();
      tmp[t] += a;
      __syncthreads();
    }
    if (i < nb) bsum[i] = carry + tmp[t] - v;
    carry += tmp[SCAN_B - 1];
    __syncthreads();
  }
}

// S(idx) = Sarr[idx] + bsum[idx>>8]  (scan3 inlined)
__device__ __forceinline__ int s_at(const int* Sarr, const int* bsum, int idx) {
  return Sarr[idx] + bsum[idx >> 8];
}

// ---- pass A3: block-local counting sort, then CONTIGUOUS per-bucket writes ----
__global__ void k_scatter_bkt(const int* __restrict__ src, const int* __restrict__ dst,
                              const int* __restrict__ Sarr, const int* __restrict__ bsum,
                              int* __restrict__ pairs) {
  __shared__ int lcnt[256];            // per-bucket count, then reused as cursor
  __shared__ int lofs[256];            // exclusive local scan
  __shared__ int base[256];            // global base for (bucket, this block)
  __shared__ int pout[EPB];            // reordered pairs (16 KB)
  __shared__ unsigned char bout[EPB];  // bucket id per output slot (4 KB)
  int t = threadIdx.x;
  int blk = blockIdx.x;
  int e0 = blk * EPB;
  int e1 = min(e0 + EPB, N_EDGES);
  int ne = e1 - e0;
  lcnt[t] = 0;
  __syncthreads();
  for (int e = e0 + t; e < e1; e += 256)
    atomicAdd(&lcnt[dst[e] >> BSHIFT], 1);
  __syncthreads();
  lofs[t] = lcnt[t];
  __syncthreads();
  for (int off = 1; off < 256; off <<= 1) {
    int v = (t >= off) ? lofs[t - off] : 0;
    __syncthreads();
    lofs[t] += v;
    __syncthreads();
  }
  lofs[t] -= lcnt[t];                               // exclusive
  base[t] = (t < NBKT) ? s_at(Sarr, bsum, t * NBLK_A + blk) : 0;
  lcnt[t] = 0;                                      // reuse as local cursor
  __syncthreads();
  for (int e = e0 + t; e < e1; e += 256) {
    int d = dst[e], s = src[e];
    int b = d >> BSHIFT;
    int r = atomicAdd(&lcnt[b], 1);
    int q = lofs[b] + r;
    pout[q] = ((d & (BSIZE - 1)) << 19) | s;        // s < 2^19, dlow 11 bits
    bout[q] = (unsigned char)b;                     // NBKT=245 <= 255
  }
  __syncthreads();
  for (int li = t; li < ne; li += 256) {
    int b = bout[li];
    pairs[base[b] + (li - lofs[b])] = pout[li];
  }
}

// ---- pass B: per-HALF-bucket CSR finalize, LDS-staged CONTIGUOUS ssrc writes ----
__global__ void __launch_bounds__(1024)
k_csr(const int* __restrict__ pairs, const int* __restrict__ Sarr,
      const int* __restrict__ bsum, const float* __restrict__ x,
      int* __restrict__ ssrc, int* __restrict__ offs,
      float* __restrict__ dinv, unsigned* __restrict__ xsb) {
  __shared__ int hist[8192];           // 8 tiles x 1024 nodes, 32 KB
  __shared__ int sout[CAP];            // 80 KB staged output
  __shared__ int tmp[1024];
  int t = threadIdx.x;
  int bkt = blockIdx.x >> 1;
  int h = blockIdx.x & 1;
  int e0 = s_at(Sarr, bsum, bkt * NBLK_A);
  int e1 = (bkt + 1 < NBKT) ? s_at(Sarr, bsum, (bkt + 1) * NBLK_A) : N_EDGES;
#pragma unroll
  for (int j = 0; j < 8; ++j) hist[t + (j << 10)] = 0;
  __syncthreads();
  int lc = 0;                          // count of low-half edges (used by h==1)
  for (int e = e0 + t; e < e1; e += 1024) {
    int p = pairs[e];
    int nl = p >> 19;                  // 11-bit node-low
    int s = p & 0x7FFFF;
    if ((nl >> 10) == h) atomicAdd(&hist[((s >> TSH) << 10) | (nl & 1023)], 1);
    else if ((nl >> 10) == 0) lc++;
  }
  tmp[t] = lc;
  __syncthreads();
  for (int off = 512; off > 0; off >>= 1) {
    if (t < off) tmp[t] += tmp[t + off];
    __syncthreads();
  }
  int halfbase = h ? tmp[0] : 0;
  __syncthreads();
  int c[8];
  int tsum = 0;
#pragma unroll
  for (int j = 0; j < 8; ++j) { c[j] = hist[(j << 10) | t]; tsum += c[j]; }
  tmp[t] = tsum;
  __syncthreads();
  for (int off = 1; off < 1024; off <<= 1) {
    int a = (t >= off) ? tmp[t - off] : 0;
    __syncthreads();
    tmp[t] += a;
    __syncthreads();
  }
  int run = tmp[t] - tsum;             // exclusive within half
  int total = tmp[1023];
  {
    int b = run;
#pragma unroll
    for (int j = 0; j < 8; ++j) { int cc = c[j]; hist[(j << 10) | t] = b; b += cc; }
  }
  int n = (bkt << BSHIFT) + (h << 10) + t;
  if (n < N_NODES) {
    offs[n] = e0 + halfbase + run;
    float di = rsqrtf((float)tsum + 1.0f);
    dinv[n] = di;
    const float* xs = x + (size_t)n * 3;
    uint2 v = make_uint2(packbf(di * xs[0], di * xs[1]), packbf(di * xs[2], 0.0f));
    *(uint2*)(xsb + (size_t)n * 2) = v;
  }
  __syncthreads();
  int base = e0 + halfbase;
  if (total <= CAP) {
    for (int e = e0 + t; e < e1; e += 1024) {
      int p = pairs[e];
      int nl = p >> 19;
      if ((nl >> 10) != h) continue;
      int s = p & 0x7FFFF;
      int r = atomicAdd(&hist[((s >> TSH) << 10) | (nl & 1023)], 1);
      sout[r] = s;
    }
    __syncthreads();
    for (int q = t; q < total; q += 1024)
      ssrc[base + q] = sout[q];
  } else {
    for (int e = e0 + t; e < e1; e += 1024) {
      int p = pairs[e];
      int nl = p >> 19;
      if ((nl >> 10) != h) continue;
      int s = p & 0x7FFFF;
      int r = atomicAdd(&hist[((s >> TSH) << 10) | (nl & 1023)], 1);
      ssrc[base + r] = s;
    }
  }
  if (bkt == 0 && h == 0 && t == 0) offs[N_NODES] = N_EDGES;
}

// ---- FUSED layer-1 gather + finalize: 2 lanes/node; u stored as TWO fp8 half-tables ----
__global__ void k_g1f1(const int* __restrict__ ssrc, const int* __restrict__ offs,
                       const unsigned* __restrict__ xsb, const float* __restrict__ dinv,
                       const float* __restrict__ W1, const float* __restrict__ b1,
                       unsigned* __restrict__ ub0, unsigned* __restrict__ ub1) {
  unsigned t = blockIdx.x * blockDim.x + threadIdx.x;
  unsigned n = t >> 1;
  int j = t & 1;
  if (n >= (unsigned)N_NODES) return;
  int o0 = offs[n], o1 = offs[n + 1];
  float a0 = 0.0f, a1 = 0.0f;
  int i = o0;
  for (; i + 1 < o1; i += 2) {
    int s0 = ssrc[i], s1 = ssrc[i + 1];
    unsigned q0 = xsb[(size_t)s0 * 2 + j];
    unsigned q1 = xsb[(size_t)s1 * 2 + j];
    a0 += bf_lo(q0) + bf_lo(q1);
    a1 += bf_hi(q0) + bf_hi(q1);
  }
  if (i < o1) {
    unsigned q = xsb[(size_t)ssrc[i] * 2 + j];
    a0 += bf_lo(q); a1 += bf_hi(q);
  }
  float oth0 = __shfl_xor(a0, 1);
  float oth1 = __shfl_xor(a1, 1);
  float A0 = j ? oth0 : a0;
  float A1v = j ? oth1 : a1;
  float A2v = j ? a0 : oth0;
  float di = dinv[n];
  uint2 xq = *(const uint2*)&xsb[(size_t)n * 2];
  float t0 = di * (A0 + bf_lo(xq.x));
  float t1 = di * (A1v + bf_hi(xq.x));
  float t2 = di * (A2v + bf_lo(xq.y));
  unsigned w0 = 0, w1 = 0;
#pragma unroll
  for (int q8 = 0; q8 < 4; ++q8) {
    int f = 8 * j + 2 * q8;
    float v0 = t0 * W1[f]     + t1 * W1[16 + f]     + t2 * W1[32 + f]     + b1[f];
    float v1 = t0 * W1[f + 1] + t1 * W1[16 + f + 1] + t2 * W1[32 + f + 1] + b1[f + 1];
    unsigned pb = f2e4m3(di * fmaxf(v0, 0.0f)) | (f2e4m3(di * fmaxf(v1, 0.0f)) << 8);
    if (q8 < 2) w0 |= pb << (16 * q8); else w1 |= pb << (16 * (q8 - 2));
  }
  unsigned* ubt = j ? ub1 : ub0;                  // j=0: features 0-7, j=1: 8-15
  *(uint2*)&ubt[(size_t)n * 2] = make_uint2(w0, w1);
}

// ---- layer 2 gather, HALF-table (4MB = one XCD L2): 2 lanes/node, LUT decode ----
__global__ void k_gather2h(const int* __restrict__ ssrc, const int* __restrict__ offs,
                           const unsigned* __restrict__ ubt, float* __restrict__ A2h) {
  __shared__ float lut[128];
  if (threadIdx.x < 128) lut[threadIdx.x] = e4m3f(threadIdx.x);
  __syncthreads();
  unsigned t = blockIdx.x * blockDim.x + threadIdx.x;
  unsigned n = t >> 1;
  int j = t & 1;
  if (n >= (unsigned)N_NODES) return;
  int o0 = offs[n], o1 = offs[n + 1];
  unsigned qs = ubt[(size_t)n * 2 + j];           // self-loop as acc init
  float a0 = lut[qs & 0x7F];
  float a1 = lut[(qs >> 8) & 0x7F];
  float a2 = lut[(qs >> 16) & 0x7F];
  float a3 = lut[(qs >> 24) & 0x7F];
  int i = o0;
  for (; i + 1 < o1; i += 2) {
    int s0 = ssrc[i], s1 = ssrc[i + 1];
    unsigned q0 = ubt[(size_t)s0 * 2 + j];
    unsigned q1 = ubt[(size_t)s1 * 2 + j];
    a0 += lut[q0 & 0x7F]         + lut[q1 & 0x7F];
    a1 += lut[(q0 >> 8) & 0x7F]  + lut[(q1 >> 8) & 0x7F];
    a2 += lut[(q0 >> 16) & 0x7F] + lut[(q1 >> 16) & 0x7F];
    a3 += lut[(q0 >> 24) & 0x7F] + lut[(q1 >> 24) & 0x7F];
  }
  if (i < o1) {
    unsigned q = ubt[(size_t)ssrc[i] * 2 + j];
    a0 += lut[q & 0x7F];
    a1 += lut[(q >> 8) & 0x7F];
    a2 += lut[(q >> 16) & 0x7F];
    a3 += lut[(q >> 24) & 0x7F];
  }
  *(float4*)&A2h[(size_t)n * 8 + j * 4] = make_float4(a0, a1, a2, a3);
}

// ---- pool v3: reads the two A2 halves; no fp8 decode, di factored out ----
__global__ void k_pool2(const float* __restrict__ A2a, const float* __restrict__ A2b,
                        const float* __restrict__ W2, const float* __restrict__ b2,
                        const float* __restrict__ dinv, const int* __restrict__ batch,
                        float* __restrict__ sums) {
  int f = threadIdx.x & 31, sub = threadIdx.x >> 5;
  int n0 = blockIdx.x * 128 + sub * 16;
  int n1 = min(n0 + 16, N_NODES);
  if (n0 >= n1) return;
  float w2col[16];
#pragma unroll
  for (int k = 0; k < 16; ++k) w2col[k] = W2[k * 32 + f];
  float bf = b2[f];
  int cur = batch[n0];
  float acc = 0.0f;
  for (int n = n0; n < n1; ++n) {
    int g = batch[n];
    if (g != cur) { atomicAdd(&sums[(size_t)cur * 32 + f], acc); acc = 0.0f; cur = g; }
    const float4* pa = (const float4*)(A2a + (size_t)n * 8);
    const float4* pb = (const float4*)(A2b + (size_t)n * 8);
    float4 aa0 = pa[0], aa1 = pa[1], aa2 = pb[0], aa3 = pb[1];
    float v = aa0.x * w2col[0]  + aa0.y * w2col[1]  + aa0.z * w2col[2]  + aa0.w * w2col[3]
            + aa1.x * w2col[4]  + aa1.y * w2col[5]  + aa1.z * w2col[6]  + aa1.w * w2col[7]
            + aa2.x * w2col[8]  + aa2.y * w2col[9]  + aa2.z * w2col[10] + aa2.w * w2col[11]
            + aa3.x * w2col[12] + aa3.y * w2col[13] + aa3.z * w2col[14] + aa3.w * w2col[15];
    v = dinv[n] * v + bf;
    acc += fmaxf(v, 0.0f);
  }
  atomicAdd(&sums[(size_t)cur * 32 + f], acc);
}

// ---- final MLP + log_softmax, with FUSED segment bounds (binary search) ----
__global__ void k_mlp(const float* __restrict__ sums, const int* __restrict__ batch,
                      const float* __restrict__ fW1, const float* __restrict__ fb1,
                      const float* __restrict__ fW2, const float* __restrict__ fb2,
                      float* __restrict__ out) {
  __shared__ float w1s[32 * 64];
  __shared__ float w2s[64 * 3];
  __shared__ float b1s[64];
  __shared__ float b2s[3];
  for (int i = threadIdx.x; i < 32 * 64; i += blockDim.x) w1s[i] = fW1[i];
  for (int i = threadIdx.x; i < 64 * 3; i += blockDim.x) w2s[i] = fW2[i];
  for (int i = threadIdx.x; i < 64; i += blockDim.x) b1s[i] = fb1[i];
  for (int i = threadIdx.x; i < 3; i += blockDim.x) b2s[i] = fb2[i];
  __syncthreads();
  int g = blockIdx.x * blockDim.x + threadIdx.x;
  if (g >= NUM_GRAPHS) return;
  int lo = 0, hi = N_NODES;
  while (lo < hi) { int mid = (lo + hi) >> 1; if (batch[mid] < g) lo = mid + 1; else hi = mid; }
  int s0 = lo;
  int lo2 = s0, hi2 = N_NODES;
  while (lo2 < hi2) { int mid = (lo2 + hi2) >> 1; if (batch[mid] < g + 1) lo2 = mid + 1; else hi2 = mid; }
  float c = fmaxf((float)(lo2 - s0), 1.0f);
  float p[32];
#pragma unroll
  for (int i = 0; i < 32; ++i) p[i] = sums[(size_t)g * 32 + i] / c;
  float z2[3] = {b2s[0], b2s[1], b2s[2]};
  for (int j = 0; j < 64; ++j) {
    float a = b1s[j];
#pragma unroll
    for (int i = 0; i < 32; ++i) a += p[i] * w1s[i * 64 + j];
    a = fmaxf(a, 0.0f);
#pragma unroll
    for (int k = 0; k < 3; ++k) z2[k] += a * w2s[j * 3 + k];
  }
  float m = fmaxf(fmaxf(z2[0], z2[1]), z2[2]);
  float l = logf(expf(z2[0] - m) + expf(z2[1] - m) + expf(z2[2] - m));
#pragma unroll
  for (int k = 0; k < 3; ++k) out[(size_t)g * 3 + k] = z2[k] - m - l;
}

extern "C" void kernel_launch(void* const* d_in, const int* in_sizes, int n_in,
                              void* d_out, int out_size, void* d_ws, size_t ws_size,
                              hipStream_t stream) {
  const float* x     = (const float*)d_in[0];
  const int*   ei    = (const int*)d_in[1];   // [2, E]
  const int*   batch = (const int*)d_in[2];
  const float* W1    = (const float*)d_in[3];
  const float* b1    = (const float*)d_in[4];
  const float* W2    = (const float*)d_in[5];
  const float* b2    = (const float*)d_in[6];
  const float* fW1   = (const float*)d_in[7];
  const float* fb1   = (const float*)d_in[8];
  const float* fW2   = (const float*)d_in[9];
  const float* fb2   = (const float*)d_in[10];
  const int* src = ei;
  const int* dst = ei + N_EDGES;

  // ---- workspace layout (≈95 MB) ----
  float* ws       = (float*)d_ws;
  float* dinv     = ws;                           // 524,288 f
  unsigned* xsb   = (unsigned*)(dinv + 524288);   // 1,048,576 u32 (2/node)
  unsigned* ub0   = xsb + 1048576;                // 1,048,576 u32 (features 0-7, 4MB)
  unsigned* ub1   = ub0 + 1048576;                // 1,048,576 u32 (features 8-15, 4MB)
  float* scratch  = (float*)(xsb + 1048576 + 4194304);  // 2,000,000 f (scan scratch)
  float* sums     = scratch + 2000000;            // 16384
  int* offs       = (int*)(sums + 16384);         // 524,288 (N_NODES+1 used)
  int* ssrc       = offs + 524288;                // 8,000,000
  int* pairs      = ssrc + 8000000;               // 8,000,000
  // aliases (dead ranges reused):
  int* H    = (int*)scratch;                      // NH = 478,730
  int* Sarr = H + 478730;                         // 478,730
  int* bsum = Sarr + 478730;                      // 1871  (total 959,331 < 2,000,000)
  float* A2a = (float*)pairs;                     // 4,000,000 f (pairs dead after k_csr)
  float* A2b = A2a + 4000000;                     // 4,000,000 f

  hipMemsetAsync(sums, 0, (size_t)NUM_GRAPHS * 32 * 4, stream);

  const int B = 256;
  k_hist<<<NBLK_A, B, 0, stream>>>(dst, H);
  k_scan1<<<NSB, SCAN_B, 0, stream>>>(H, Sarr, bsum, NH);
  k_scan2<<<1, SCAN_B, 0, stream>>>(bsum, NSB);
  k_scatter_bkt<<<NBLK_A, B, 0, stream>>>(src, dst, Sarr, bsum, pairs);
  k_csr<<<NBKT * 2, 1024, 0, stream>>>(pairs, Sarr, bsum, x, ssrc, offs, dinv, xsb);
  k_g1f1<<<((size_t)N_NODES * 2 + B - 1) / B, B, 0, stream>>>(ssrc, offs, xsb, dinv, W1, b1, ub0, ub1);
  k_gather2h<<<((size_t)N_NODES * 2 + B - 1) / B, B, 0, stream>>>(ssrc, offs, ub0, A2a);
  k_gather2h<<<((size_t)N_NODES * 2 + B - 1) / B, B, 0, stream>>>(ssrc, offs, ub1, A2b);
  k_pool2<<<(N_NODES + 127) / 128, B, 0, stream>>>(A2a, A2b, W2, b2, dinv, batch, sums);
  k_mlp<<<(NUM_GRAPHS + B - 1) / B, B, 0, stream>>>(sums, batch, fW1, fb1, fW2, fb2, (float*)d_out);
}

// Round 20
// 366.103 us; speedup vs baseline: 1.1270x; 1.1270x over previous
//
#include <hip/hip_runtime.h>
#include <hip/hip_bf16.h>

constexpr int N_NODES    = 500000;
constexpr int N_EDGES    = 8000000;
constexpr int NUM_GRAPHS = 512;

constexpr int BSHIFT = 11;                              // 2048 nodes / coarse bucket
constexpr int BSIZE  = 1 << BSHIFT;
constexpr int NBKT   = (N_NODES + BSIZE - 1) / BSIZE;   // 245
constexpr int EPB    = 8192;                            // edges per block (pass A)
constexpr int NBLK_A = (N_EDGES + EPB - 1) / EPB;       // 977
constexpr int NH     = NBKT * NBLK_A;                   // 239,365
constexpr int SCAN_B = 256;
constexpr int NSB    = (NH + SCAN_B - 1) / SCAN_B;      // 935
constexpr int TSH    = 16;                              // src-tile = 65536 nodes (1MB fp8 ub)
constexpr int CAP    = 20480;                           // LDS sout capacity

// ---- bf16 helpers (bit-level, RNE pack) ----
__device__ __forceinline__ float bf_lo(unsigned u) { return __uint_as_float(u << 16); }
__device__ __forceinline__ float bf_hi(unsigned u) { return __uint_as_float(u & 0xFFFF0000u); }
__device__ __forceinline__ unsigned short f2bf(float f) {
  unsigned u = __float_as_uint(f);
  return (unsigned short)((u + 0x7FFFu + ((u >> 16) & 1u)) >> 16);
}
__device__ __forceinline__ unsigned packbf(float a, float b) {
  return (unsigned)f2bf(a) | ((unsigned)f2bf(b) << 16);
}

// ---- fp8 e4m3fn helpers (values >= 0 only; sign elided) ----
__device__ __forceinline__ unsigned f2e4m3(float x) {
  x = fminf(x, 448.0f);
  unsigned xb = __float_as_uint(x);
  int e = (int)(xb >> 23) - 127;
  if (e < -6) {                               // denormal grid: step 2^-9
    int m = (int)rintf(x * 512.0f);           // 0..8
    return (m <= 7) ? (unsigned)m : 0x08u;    // 8 -> smallest normal 2^-6
  }
  unsigned lsb = (xb >> 20) & 1;
  unsigned r = xb + 0x7FFFFu + lsb;           // RNE into 3-bit mantissa (carry-safe)
  int e2 = (int)(r >> 23) - 127;
  unsigned m3 = (r >> 20) & 7;
  return (unsigned)(((e2 + 7) << 3) | m3);
}
__device__ __forceinline__ float e4m3f(unsigned b) {
  unsigned e = (b >> 3) & 0xF, m = b & 7;
  float norm = __uint_as_float(((e + 120u) << 23) | (m << 20));
  float den = (float)m * 0.001953125f;        // m * 2^-9
  return e ? norm : den;
}

// ---- pass A1: per-block coarse histogram (LDS atomics only) ----
__global__ void k_hist(const int* __restrict__ dst, int* __restrict__ H) {
  __shared__ int h[NBKT];
  for (int i = threadIdx.x; i < NBKT; i += blockDim.x) h[i] = 0;
  __syncthreads();
  int e0 = blockIdx.x * EPB;
  int e1 = min(e0 + EPB, N_EDGES);
  for (int e = e0 + threadIdx.x; e < e1; e += blockDim.x)
    atomicAdd(&h[dst[e] >> BSHIFT], 1);
  __syncthreads();
  for (int i = threadIdx.x; i < NBKT; i += blockDim.x)
    H[i * NBLK_A + blockIdx.x] = h[i];                  // bucket-major
}

// ---- exclusive scan of H: 2 kernels (scan3 folded into consumers) ----
__global__ void k_scan1(const int* __restrict__ in, int* __restrict__ out,
                        int* __restrict__ bsum, int n) {
  __shared__ int tmp[SCAN_B];
  int t = threadIdx.x;
  int i = blockIdx.x * SCAN_B + t;
  int v = (i < n) ? in[i] : 0;
  tmp[t] = v;
  __syncthreads();
  for (int off = 1; off < SCAN_B; off <<= 1) {
    int a = (t >= off) ? tmp[t - off] : 0;
    __syncthreads();
    tmp[t] += a;
    __syncthreads();
  }
  if (i < n) out[i] = tmp[t] - v;
  if (t == SCAN_B - 1) bsum[blockIdx.x] = tmp[t];
}

__global__ void k_scan2(int* __restrict__ bsum, int nb) {  // in-place exclusive
  __shared__ int tmp[SCAN_B];
  int t = threadIdx.x;
  int carry = 0;
  for (int base = 0; base < nb; base += SCAN_B) {
    int i = base + t;
    int v = (i < nb) ? bsum[i] : 0;
    tmp[t] = v;
    __syncthreads();
    for (int off = 1; off < SCAN_B; off <<= 1) {
      int a = (t >= off) ? tmp[t - off] : 0;
      __syncthreads();
      tmp[t] += a;
      __syncthreads();
    }
    if (i < nb) bsum[i] = carry + tmp[t] - v;
    carry += tmp[SCAN_B - 1];
    __syncthreads();
  }
}

// S(idx) = Sarr[idx] + bsum[idx>>8]  (scan3 inlined)
__device__ __forceinline__ int s_at(const int* Sarr, const int* bsum, int idx) {
  return Sarr[idx] + bsum[idx >> 8];
}

// ---- pass A3: block-local counting sort, then CONTIGUOUS per-bucket writes ----
__global__ void k_scatter_bkt(const int* __restrict__ src, const int* __restrict__ dst,
                              const int* __restrict__ Sarr, const int* __restrict__ bsum,
                              int* __restrict__ pairs) {
  __shared__ int lcnt[256];            // per-bucket count, then reused as cursor
  __shared__ int lofs[256];            // exclusive local scan
  __shared__ int base[256];            // global base for (bucket, this block)
  __shared__ int pout[EPB];            // reordered pairs (32 KB)
  __shared__ unsigned char bout[EPB];  // bucket id per output slot (8 KB)
  int t = threadIdx.x;
  int blk = blockIdx.x;
  int e0 = blk * EPB;
  int e1 = min(e0 + EPB, N_EDGES);
  int ne = e1 - e0;
  lcnt[t] = 0;
  __syncthreads();
  for (int e = e0 + t; e < e1; e += 256)
    atomicAdd(&lcnt[dst[e] >> BSHIFT], 1);
  __syncthreads();
  lofs[t] = lcnt[t];
  __syncthreads();
  for (int off = 1; off < 256; off <<= 1) {
    int v = (t >= off) ? lofs[t - off] : 0;
    __syncthreads();
    lofs[t] += v;
    __syncthreads();
  }
  lofs[t] -= lcnt[t];                               // exclusive
  base[t] = (t < NBKT) ? s_at(Sarr, bsum, t * NBLK_A + blk) : 0;
  lcnt[t] = 0;                                      // reuse as local cursor
  __syncthreads();
  for (int e = e0 + t; e < e1; e += 256) {
    int d = dst[e], s = src[e];
    int b = d >> BSHIFT;
    int r = atomicAdd(&lcnt[b], 1);
    int q = lofs[b] + r;
    pout[q] = ((d & (BSIZE - 1)) << 19) | s;        // s < 2^19, dlow 11 bits
    bout[q] = (unsigned char)b;                     // NBKT=245 <= 255
  }
  __syncthreads();
  for (int li = t; li < ne; li += 256) {
    int b = bout[li];
    pairs[base[b] + (li - lofs[b])] = pout[li];
  }
}

// ---- pass B: per-HALF-bucket CSR finalize, LDS-staged CONTIGUOUS ssrc writes ----
__global__ void __launch_bounds__(1024)
k_csr(const int* __restrict__ pairs, const int* __restrict__ Sarr,
      const int* __restrict__ bsum, const float* __restrict__ x,
      int* __restrict__ ssrc, int* __restrict__ offs,
      float* __restrict__ dinv, unsigned* __restrict__ xsb) {
  __shared__ int hist[8192];           // 8 tiles x 1024 nodes, 32 KB
  __shared__ int sout[CAP];            // 80 KB staged output
  __shared__ int tmp[1024];
  int t = threadIdx.x;
  int bkt = blockIdx.x >> 1;
  int h = blockIdx.x & 1;
  int e0 = s_at(Sarr, bsum, bkt * NBLK_A);
  int e1 = (bkt + 1 < NBKT) ? s_at(Sarr, bsum, (bkt + 1) * NBLK_A) : N_EDGES;
#pragma unroll
  for (int j = 0; j < 8; ++j) hist[t + (j << 10)] = 0;
  __syncthreads();
  int lc = 0;                          // count of low-half edges (used by h==1)
  for (int e = e0 + t; e < e1; e += 1024) {
    int p = pairs[e];
    int nl = p >> 19;                  // 11-bit node-low
    int s = p & 0x7FFFF;
    if ((nl >> 10) == h) atomicAdd(&hist[((s >> TSH) << 10) | (nl & 1023)], 1);
    else if ((nl >> 10) == 0) lc++;
  }
  tmp[t] = lc;
  __syncthreads();
  for (int off = 512; off > 0; off >>= 1) {
    if (t < off) tmp[t] += tmp[t + off];
    __syncthreads();
  }
  int halfbase = h ? tmp[0] : 0;
  __syncthreads();
  int c[8];
  int tsum = 0;
#pragma unroll
  for (int j = 0; j < 8; ++j) { c[j] = hist[(j << 10) | t]; tsum += c[j]; }
  tmp[t] = tsum;
  __syncthreads();
  for (int off = 1; off < 1024; off <<= 1) {
    int a = (t >= off) ? tmp[t - off] : 0;
    __syncthreads();
    tmp[t] += a;
    __syncthreads();
  }
  int run = tmp[t] - tsum;             // exclusive within half
  int total = tmp[1023];
  {
    int b = run;
#pragma unroll
    for (int j = 0; j < 8; ++j) { int cc = c[j]; hist[(j << 10) | t] = b; b += cc; }
  }
  int n = (bkt << BSHIFT) + (h << 10) + t;
  if (n < N_NODES) {
    offs[n] = e0 + halfbase + run;
    float di = rsqrtf((float)tsum + 1.0f);
    dinv[n] = di;
    const float* xs = x + (size_t)n * 3;
    uint2 v = make_uint2(packbf(di * xs[0], di * xs[1]), packbf(di * xs[2], 0.0f));
    *(uint2*)(xsb + (size_t)n * 2) = v;
  }
  __syncthreads();
  int base = e0 + halfbase;
  if (total <= CAP) {
    for (int e = e0 + t; e < e1; e += 1024) {
      int p = pairs[e];
      int nl = p >> 19;
      if ((nl >> 10) != h) continue;
      int s = p & 0x7FFFF;
      int r = atomicAdd(&hist[((s >> TSH) << 10) | (nl & 1023)], 1);
      sout[r] = s;
    }
    __syncthreads();
    for (int q = t; q < total; q += 1024)
      ssrc[base + q] = sout[q];
  } else {
    for (int e = e0 + t; e < e1; e += 1024) {
      int p = pairs[e];
      int nl = p >> 19;
      if ((nl >> 10) != h) continue;
      int s = p & 0x7FFFF;
      int r = atomicAdd(&hist[((s >> TSH) << 10) | (nl & 1023)], 1);
      ssrc[base + r] = s;
    }
  }
  if (bkt == 0 && h == 0 && t == 0) offs[N_NODES] = N_EDGES;
}

// ---- FUSED layer-1 gather + finalize: 2 lanes/node, UNROLL-4; u stored fp8 (16B/row) ----
__global__ void k_g1f1(const int* __restrict__ ssrc, const int* __restrict__ offs,
                       const unsigned* __restrict__ xsb, const float* __restrict__ dinv,
                       const float* __restrict__ W1, const float* __restrict__ b1,
                       unsigned* __restrict__ ub) {
  unsigned t = blockIdx.x * blockDim.x + threadIdx.x;
  unsigned n = t >> 1;
  int j = t & 1;
  if (n >= (unsigned)N_NODES) return;
  int o0 = offs[n], o1 = offs[n + 1];
  float a0 = 0.0f, a1 = 0.0f;
  int i = o0;
  for (; i + 3 < o1; i += 4) {
    int s0 = ssrc[i], s1 = ssrc[i + 1], s2 = ssrc[i + 2], s3 = ssrc[i + 3];
    unsigned q0 = xsb[(size_t)s0 * 2 + j];
    unsigned q1 = xsb[(size_t)s1 * 2 + j];
    unsigned q2 = xsb[(size_t)s2 * 2 + j];
    unsigned q3 = xsb[(size_t)s3 * 2 + j];
    a0 += bf_lo(q0) + bf_lo(q1) + bf_lo(q2) + bf_lo(q3);
    a1 += bf_hi(q0) + bf_hi(q1) + bf_hi(q2) + bf_hi(q3);
  }
  for (; i < o1; ++i) {
    unsigned q = xsb[(size_t)ssrc[i] * 2 + j];
    a0 += bf_lo(q); a1 += bf_hi(q);
  }
  float oth0 = __shfl_xor(a0, 1);
  float oth1 = __shfl_xor(a1, 1);
  float A0 = j ? oth0 : a0;
  float A1v = j ? oth1 : a1;
  float A2v = j ? a0 : oth0;
  float di = dinv[n];
  uint2 xq = *(const uint2*)&xsb[(size_t)n * 2];
  float t0 = di * (A0 + bf_lo(xq.x));
  float t1 = di * (A1v + bf_hi(xq.x));
  float t2 = di * (A2v + bf_lo(xq.y));
  unsigned w0 = 0, w1 = 0;
#pragma unroll
  for (int q8 = 0; q8 < 4; ++q8) {
    int f = 8 * j + 2 * q8;
    float v0 = t0 * W1[f]     + t1 * W1[16 + f]     + t2 * W1[32 + f]     + b1[f];
    float v1 = t0 * W1[f + 1] + t1 * W1[16 + f + 1] + t2 * W1[32 + f + 1] + b1[f + 1];
    unsigned pb = f2e4m3(di * fmaxf(v0, 0.0f)) | (f2e4m3(di * fmaxf(v1, 0.0f)) << 8);
    if (q8 < 2) w0 |= pb << (16 * q8); else w1 |= pb << (16 * (q8 - 2));
  }
  *(uint2*)&ub[(size_t)n * 4 + j * 2] = make_uint2(w0, w1);
}

// ---- layer 2 gather: 4 lanes/node, LDS-LUT fp8 decode, self-loop u folded in ----
__global__ void k_gather2(const int* __restrict__ ssrc, const int* __restrict__ offs,
                          const unsigned* __restrict__ ub, float* __restrict__ A2) {
  __shared__ float lut[128];
  if (threadIdx.x < 128) lut[threadIdx.x] = e4m3f(threadIdx.x);
  __syncthreads();
  unsigned t = blockIdx.x * blockDim.x + threadIdx.x;
  unsigned n = t >> 2;
  int j = t & 3;
  if (n >= (unsigned)N_NODES) return;
  int o0 = offs[n], o1 = offs[n + 1];
  unsigned qs = ub[(size_t)n * 4 + j];                  // self-loop u[n] as acc init
  float a0 = lut[qs & 0x7F];
  float a1 = lut[(qs >> 8) & 0x7F];
  float a2 = lut[(qs >> 16) & 0x7F];
  float a3 = lut[(qs >> 24) & 0x7F];
  int i = o0;
  for (; i + 1 < o1; i += 2) {
    int s0 = ssrc[i], s1 = ssrc[i + 1];
    unsigned q0 = ub[(size_t)s0 * 4 + j];
    unsigned q1 = ub[(size_t)s1 * 4 + j];
    a0 += lut[q0 & 0x7F]         + lut[q1 & 0x7F];
    a1 += lut[(q0 >> 8) & 0x7F]  + lut[(q1 >> 8) & 0x7F];
    a2 += lut[(q0 >> 16) & 0x7F] + lut[(q1 >> 16) & 0x7F];
    a3 += lut[(q0 >> 24) & 0x7F] + lut[(q1 >> 24) & 0x7F];
  }
  if (i < o1) {
    unsigned q = ub[(size_t)ssrc[i] * 4 + j];
    a0 += lut[q & 0x7F];
    a1 += lut[(q >> 8) & 0x7F];
    a2 += lut[(q >> 16) & 0x7F];
    a3 += lut[(q >> 24) & 0x7F];
  }
  *(float4*)&A2[(size_t)n * 16 + j * 4] = make_float4(a0, a1, a2, a3);
}

// ---- pool v3: A2 already includes self-loop u; no fp8 decode, di factored out ----
__global__ void k_pool2(const float* __restrict__ A2,
                        const float* __restrict__ W2, const float* __restrict__ b2,
                        const float* __restrict__ dinv, const int* __restrict__ batch,
                        float* __restrict__ sums) {
  int f = threadIdx.x & 31, sub = threadIdx.x >> 5;
  int n0 = blockIdx.x * 128 + sub * 16;
  int n1 = min(n0 + 16, N_NODES);
  if (n0 >= n1) return;
  float w2col[16];
#pragma unroll
  for (int k = 0; k < 16; ++k) w2col[k] = W2[k * 32 + f];
  float bf = b2[f];
  int cur = batch[n0];
  float acc = 0.0f;
  for (int n = n0; n < n1; ++n) {
    int g = batch[n];
    if (g != cur) { atomicAdd(&sums[(size_t)cur * 32 + f], acc); acc = 0.0f; cur = g; }
    const float4* a2p = (const float4*)(A2 + (size_t)n * 16);
    float4 aa0 = a2p[0], aa1 = a2p[1], aa2 = a2p[2], aa3 = a2p[3];
    float v = aa0.x * w2col[0]  + aa0.y * w2col[1]  + aa0.z * w2col[2]  + aa0.w * w2col[3]
            + aa1.x * w2col[4]  + aa1.y * w2col[5]  + aa1.z * w2col[6]  + aa1.w * w2col[7]
            + aa2.x * w2col[8]  + aa2.y * w2col[9]  + aa2.z * w2col[10] + aa2.w * w2col[11]
            + aa3.x * w2col[12] + aa3.y * w2col[13] + aa3.z * w2col[14] + aa3.w * w2col[15];
    v = dinv[n] * v + bf;
    acc += fmaxf(v, 0.0f);
  }
  atomicAdd(&sums[(size_t)cur * 32 + f], acc);
}

// ---- final MLP + log_softmax, with FUSED segment bounds (binary search) ----
__global__ void k_mlp(const float* __restrict__ sums, const int* __restrict__ batch,
                      const float* __restrict__ fW1, const float* __restrict__ fb1,
                      const float* __restrict__ fW2, const float* __restrict__ fb2,
                      float* __restrict__ out) {
  __shared__ float w1s[32 * 64];
  __shared__ float w2s[64 * 3];
  __shared__ float b1s[64];
  __shared__ float b2s[3];
  for (int i = threadIdx.x; i < 32 * 64; i += blockDim.x) w1s[i] = fW1[i];
  for (int i = threadIdx.x; i < 64 * 3; i += blockDim.x) w2s[i] = fW2[i];
  for (int i = threadIdx.x; i < 64; i += blockDim.x) b1s[i] = fb1[i];
  for (int i = threadIdx.x; i < 3; i += blockDim.x) b2s[i] = fb2[i];
  __syncthreads();
  int g = blockIdx.x * blockDim.x + threadIdx.x;
  if (g >= NUM_GRAPHS) return;
  int lo = 0, hi = N_NODES;
  while (lo < hi) { int mid = (lo + hi) >> 1; if (batch[mid] < g) lo = mid + 1; else hi = mid; }
  int s0 = lo;
  int lo2 = s0, hi2 = N_NODES;
  while (lo2 < hi2) { int mid = (lo2 + hi2) >> 1; if (batch[mid] < g + 1) lo2 = mid + 1; else hi2 = mid; }
  float c = fmaxf((float)(lo2 - s0), 1.0f);
  float p[32];
#pragma unroll
  for (int i = 0; i < 32; ++i) p[i] = sums[(size_t)g * 32 + i] / c;
  float z2[3] = {b2s[0], b2s[1], b2s[2]};
  for (int j = 0; j < 64; ++j) {
    float a = b1s[j];
#pragma unroll
    for (int i = 0; i < 32; ++i) a += p[i] * w1s[i * 64 + j];
    a = fmaxf(a, 0.0f);
#pragma unroll
    for (int k = 0; k < 3; ++k) z2[k] += a * w2s[j * 3 + k];
  }
  float m = fmaxf(fmaxf(z2[0], z2[1]), z2[2]);
  float l = logf(expf(z2[0] - m) + expf(z2[1] - m) + expf(z2[2] - m));
#pragma unroll
  for (int k = 0; k < 3; ++k) out[(size_t)g * 3 + k] = z2[k] - m - l;
}

extern "C" void kernel_launch(void* const* d_in, const int* in_sizes, int n_in,
                              void* d_out, int out_size, void* d_ws, size_t ws_size,
                              hipStream_t stream) {
  const float* x     = (const float*)d_in[0];
  const int*   ei    = (const int*)d_in[1];   // [2, E]
  const int*   batch = (const int*)d_in[2];
  const float* W1    = (const float*)d_in[3];
  const float* b1    = (const float*)d_in[4];
  const float* W2    = (const float*)d_in[5];
  const float* b2    = (const float*)d_in[6];
  const float* fW1   = (const float*)d_in[7];
  const float* fb1   = (const float*)d_in[8];
  const float* fW2   = (const float*)d_in[9];
  const float* fb2   = (const float*)d_in[10];
  const int* src = ei;
  const int* dst = ei + N_EDGES;

  // ---- workspace layout (≈95 MB) ----
  float* ws       = (float*)d_ws;
  float* dinv     = ws;                           // 524,288 f
  unsigned* xsb   = (unsigned*)(dinv + 524288);   // 1,048,576 u32 (2/node)
  unsigned* ub    = xsb + 1048576;                // 4,194,304 u32 slot (fp8: 4/node used)
  float* scratch  = (float*)(ub + 4194304);       // 2,000,000 f (scan scratch)
  float* sums     = scratch + 2000000;            // 16384
  int* offs       = (int*)(sums + 16384);         // 524,288 (N_NODES+1 used)
  int* ssrc       = offs + 524288;                // 8,000,000
  int* pairs      = ssrc + 8000000;               // 8,000,000
  // aliases (dead ranges reused):
  int* H    = (int*)scratch;                      // NH = 239,365
  int* Sarr = H + NH;                             // 239,365
  int* bsum = Sarr + NH;                          // 935  (total < 2,000,000)
  float* A2 = (float*)pairs;                      // pairs dead after k_csr

  hipMemsetAsync(sums, 0, (size_t)NUM_GRAPHS * 32 * 4, stream);

  const int B = 256;
  k_hist<<<NBLK_A, B, 0, stream>>>(dst, H);
  k_scan1<<<NSB, SCAN_B, 0, stream>>>(H, Sarr, bsum, NH);
  k_scan2<<<1, SCAN_B, 0, stream>>>(bsum, NSB);
  k_scatter_bkt<<<NBLK_A, B, 0, stream>>>(src, dst, Sarr, bsum, pairs);
  k_csr<<<NBKT * 2, 1024, 0, stream>>>(pairs, Sarr, bsum, x, ssrc, offs, dinv, xsb);
  k_g1f1<<<((size_t)N_NODES * 2 + B - 1) / B, B, 0, stream>>>(ssrc, offs, xsb, dinv, W1, b1, ub);
  k_gather2<<<((size_t)N_NODES * 4 + B - 1) / B, B, 0, stream>>>(ssrc, offs, ub, A2);
  k_pool2<<<(N_NODES + 127) / 128, B, 0, stream>>>(A2, W2, b2, dinv, batch, sums);
  k_mlp<<<(NUM_GRAPHS + B - 1) / B, B, 0, stream>>>(sums, batch, fW1, fb1, fW2, fb2, (float*)d_out);
}

// Round 21
// 329.597 us; speedup vs baseline: 1.2518x; 1.1108x over previous
//
#include <hip/hip_runtime.h>
#include <hip/hip_bf16.h>

constexpr int N_NODES    = 500000;
constexpr int N_EDGES    = 8000000;
constexpr int NUM_GRAPHS = 512;

constexpr int BSHIFT = 10;                              // 1024 nodes / bucket
constexpr int BSIZE  = 1 << BSHIFT;
constexpr int NBKT   = (N_NODES + BSIZE - 1) / BSIZE;   // 489
constexpr int EPB    = 8192;                            // edges per block (pass A)
constexpr int NBLK_A = (N_EDGES + EPB - 1) / EPB;       // 977
constexpr int NH     = NBKT * NBLK_A;                   // 477,753
constexpr int SCAN_B = 256;
constexpr int NSB    = (NH + SCAN_B - 1) / SCAN_B;      // 1867
constexpr int TSH    = 16;                              // src-tile = 65536 nodes (1MB fp8 ub)
constexpr int CAP    = 20480;                           // LDS sout capacity (mean 16.4K)

// ---- bf16 helpers (bit-level, RNE pack) ----
__device__ __forceinline__ float bf_lo(unsigned u) { return __uint_as_float(u << 16); }
__device__ __forceinline__ float bf_hi(unsigned u) { return __uint_as_float(u & 0xFFFF0000u); }
__device__ __forceinline__ unsigned short f2bf(float f) {
  unsigned u = __float_as_uint(f);
  return (unsigned short)((u + 0x7FFFu + ((u >> 16) & 1u)) >> 16);
}
__device__ __forceinline__ unsigned packbf(float a, float b) {
  return (unsigned)f2bf(a) | ((unsigned)f2bf(b) << 16);
}

// ---- fp8 e4m3fn helpers (values >= 0 only; sign elided) ----
__device__ __forceinline__ unsigned f2e4m3(float x) {
  x = fminf(x, 448.0f);
  unsigned xb = __float_as_uint(x);
  int e = (int)(xb >> 23) - 127;
  if (e < -6) {                               // denormal grid: step 2^-9
    int m = (int)rintf(x * 512.0f);           // 0..8
    return (m <= 7) ? (unsigned)m : 0x08u;    // 8 -> smallest normal 2^-6
  }
  unsigned lsb = (xb >> 20) & 1;
  unsigned r = xb + 0x7FFFFu + lsb;           // RNE into 3-bit mantissa (carry-safe)
  int e2 = (int)(r >> 23) - 127;
  unsigned m3 = (r >> 20) & 7;
  return (unsigned)(((e2 + 7) << 3) | m3);
}
__device__ __forceinline__ float e4m3f(unsigned b) {
  unsigned e = (b >> 3) & 0xF, m = b & 7;
  float norm = __uint_as_float(((e + 120u) << 23) | (m << 20));
  float den = (float)m * 0.001953125f;        // m * 2^-9
  return e ? norm : den;
}

// ---- pass A1: per-block coarse histogram (LDS atomics only) ----
__global__ void k_hist(const int* __restrict__ dst, int* __restrict__ H) {
  __shared__ int h[NBKT];
  for (int i = threadIdx.x; i < NBKT; i += blockDim.x) h[i] = 0;
  __syncthreads();
  int e0 = blockIdx.x * EPB;
  int e1 = min(e0 + EPB, N_EDGES);
  for (int e = e0 + threadIdx.x; e < e1; e += blockDim.x)
    atomicAdd(&h[dst[e] >> BSHIFT], 1);
  __syncthreads();
  for (int i = threadIdx.x; i < NBKT; i += blockDim.x)
    H[i * NBLK_A + blockIdx.x] = h[i];                  // bucket-major
}

// ---- exclusive scan of H: 2 kernels (scan3 folded into consumers) ----
__global__ void k_scan1(const int* __restrict__ in, int* __restrict__ out,
                        int* __restrict__ bsum, int n) {
  __shared__ int tmp[SCAN_B];
  int t = threadIdx.x;
  int i = blockIdx.x * SCAN_B + t;
  int v = (i < n) ? in[i] : 0;
  tmp[t] = v;
  __syncthreads();
  for (int off = 1; off < SCAN_B; off <<= 1) {
    int a = (t >= off) ? tmp[t - off] : 0;
    __syncthreads();
    tmp[t] += a;
    __syncthreads();
  }
  if (i < n) out[i] = tmp[t] - v;
  if (t == SCAN_B - 1) bsum[blockIdx.x] = tmp[t];
}

__global__ void k_scan2(int* __restrict__ bsum, int nb) {  // in-place exclusive
  __shared__ int tmp[SCAN_B];
  int t = threadIdx.x;
  int carry = 0;
  for (int base = 0; base < nb; base += SCAN_B) {
    int i = base + t;
    int v = (i < nb) ? bsum[i] : 0;
    tmp[t] = v;
    __syncthreads();
    for (int off = 1; off < SCAN_B; off <<= 1) {
      int a = (t >= off) ? tmp[t - off] : 0;
      __syncthreads();
      tmp[t] += a;
      __syncthreads();
    }
    if (i < nb) bsum[i] = carry + tmp[t] - v;
    carry += tmp[SCAN_B - 1];
    __syncthreads();
  }
}

// S(idx) = Sarr[idx] + bsum[idx>>8]  (scan3 inlined)
__device__ __forceinline__ int s_at(const int* Sarr, const int* bsum, int idx) {
  return Sarr[idx] + bsum[idx >> 8];
}

// ---- pass A3: block-local counting sort (counts from H, dst read ONCE) ----
__global__ void __launch_bounds__(512)
k_scatter_bkt(const int* __restrict__ src, const int* __restrict__ dst,
              const int* __restrict__ H, const int* __restrict__ Sarr,
              const int* __restrict__ bsum, int* __restrict__ pairs) {
  __shared__ int lcnt[512];              // per-bucket count, then reused as cursor
  __shared__ int lofs[512];              // exclusive local scan
  __shared__ int base[512];              // global base for (bucket, this block)
  __shared__ int pout[EPB];              // reordered pairs (32 KB)
  __shared__ unsigned short bout[EPB];   // bucket id per output slot (16 KB)
  int t = threadIdx.x;
  int blk = blockIdx.x;
  int e0 = blk * EPB;
  int e1 = min(e0 + EPB, N_EDGES);
  int ne = e1 - e0;
  int cnt = (t < NBKT) ? H[t * NBLK_A + blk] : 0;   // counts already known
  lcnt[t] = cnt;
  lofs[t] = cnt;
  base[t] = (t < NBKT) ? s_at(Sarr, bsum, t * NBLK_A + blk) : 0;
  __syncthreads();
  for (int off = 1; off < 512; off <<= 1) {
    int v = (t >= off) ? lofs[t - off] : 0;
    __syncthreads();
    lofs[t] += v;
    __syncthreads();
  }
  lofs[t] -= lcnt[t];                               // exclusive
  lcnt[t] = 0;                                      // reuse as local cursor
  __syncthreads();
  for (int e = e0 + t; e < e1; e += 512) {
    int d = dst[e], s = src[e];
    int b = d >> BSHIFT;
    int r = atomicAdd(&lcnt[b], 1);
    int q = lofs[b] + r;
    pout[q] = ((d & (BSIZE - 1)) << 19) | s;        // s < 2^19, dlow 10 bits
    bout[q] = (unsigned short)b;                    // NBKT=489
  }
  __syncthreads();
  for (int li = t; li < ne; li += 512) {
    int b = bout[li];
    pairs[base[b] + (li - lofs[b])] = pout[li];
  }
}

// ---- pass B: per-bucket CSR finalize (one block per 1024-node bucket) ----
// hist bin = (tile<<10)|node_low; output per bucket is (node, src-tile)-ordered.
__global__ void __launch_bounds__(1024)
k_csr(const int* __restrict__ pairs, const int* __restrict__ Sarr,
      const int* __restrict__ bsum, const float* __restrict__ x,
      int* __restrict__ ssrc, int* __restrict__ offs,
      float* __restrict__ dinv, unsigned* __restrict__ xsb) {
  __shared__ int hist[8192];           // 8 tiles x 1024 nodes, 32 KB
  __shared__ int sout[CAP];            // 80 KB staged output
  __shared__ int tmp[1024];
  int t = threadIdx.x;
  int bkt = blockIdx.x;
  int n0 = bkt << BSHIFT;
  int e0 = s_at(Sarr, bsum, bkt * NBLK_A);
  int e1 = (bkt + 1 < NBKT) ? s_at(Sarr, bsum, (bkt + 1) * NBLK_A) : N_EDGES;
  int total = e1 - e0;
#pragma unroll
  for (int j = 0; j < 8; ++j) hist[t + (j << 10)] = 0;
  __syncthreads();
  for (int e = e0 + t; e < e1; e += 1024) {
    int p = pairs[e];
    atomicAdd(&hist[(((p & 0x7FFFF) >> TSH) << 10) | (p >> 19)], 1);
  }
  __syncthreads();
  int c[8];
  int tsum = 0;
#pragma unroll
  for (int j = 0; j < 8; ++j) { c[j] = hist[(j << 10) | t]; tsum += c[j]; }
  tmp[t] = tsum;
  __syncthreads();
  for (int off = 1; off < 1024; off <<= 1) {
    int a = (t >= off) ? tmp[t - off] : 0;
    __syncthreads();
    tmp[t] += a;
    __syncthreads();
  }
  int run = tmp[t] - tsum;             // exclusive over nodes in bucket
  {
    int b = run;
#pragma unroll
    for (int j = 0; j < 8; ++j) { int cc = c[j]; hist[(j << 10) | t] = b; b += cc; }
  }
  int n = n0 + t;
  if (n < N_NODES) {
    offs[n] = e0 + run;
    float di = rsqrtf((float)tsum + 1.0f);
    dinv[n] = di;
    const float* xs = x + (size_t)n * 3;
    uint2 v = make_uint2(packbf(di * xs[0], di * xs[1]), packbf(di * xs[2], 0.0f));
    *(uint2*)(xsb + (size_t)n * 2) = v;
  }
  __syncthreads();
  if (total <= CAP) {
    for (int e = e0 + t; e < e1; e += 1024) {
      int p = pairs[e];
      int s = p & 0x7FFFF;
      int r = atomicAdd(&hist[((s >> TSH) << 10) | (p >> 19)], 1);
      sout[r] = s;
    }
    __syncthreads();
    for (int q = t; q < total; q += 1024)
      ssrc[e0 + q] = sout[q];
  } else {                             // statistically never (mean 16.4K, CAP 20.5K)
    for (int e = e0 + t; e < e1; e += 1024) {
      int p = pairs[e];
      int s = p & 0x7FFFF;
      int r = atomicAdd(&hist[((s >> TSH) << 10) | (p >> 19)], 1);
      ssrc[e0 + r] = s;
    }
  }
  if (bkt == 0 && t == 0) offs[N_NODES] = N_EDGES;
}

// ---- FUSED layer-1 gather + finalize: 2 lanes/node, unroll-4; u stored fp8 (16B/row) ----
__global__ void k_g1f1(const int* __restrict__ ssrc, const int* __restrict__ offs,
                       const unsigned* __restrict__ xsb, const float* __restrict__ dinv,
                       const float* __restrict__ W1, const float* __restrict__ b1,
                       unsigned* __restrict__ ub) {
  unsigned t = blockIdx.x * blockDim.x + threadIdx.x;
  unsigned n = t >> 1;
  int j = t & 1;
  if (n >= (unsigned)N_NODES) return;
  int o0 = offs[n], o1 = offs[n + 1];
  float a0 = 0.0f, a1 = 0.0f;
  int i = o0;
  for (; i + 3 < o1; i += 4) {
    int s0 = ssrc[i], s1 = ssrc[i + 1], s2 = ssrc[i + 2], s3 = ssrc[i + 3];
    unsigned q0 = xsb[(size_t)s0 * 2 + j];
    unsigned q1 = xsb[(size_t)s1 * 2 + j];
    unsigned q2 = xsb[(size_t)s2 * 2 + j];
    unsigned q3 = xsb[(size_t)s3 * 2 + j];
    a0 += bf_lo(q0) + bf_lo(q1) + bf_lo(q2) + bf_lo(q3);
    a1 += bf_hi(q0) + bf_hi(q1) + bf_hi(q2) + bf_hi(q3);
  }
  for (; i < o1; ++i) {
    unsigned q = xsb[(size_t)ssrc[i] * 2 + j];
    a0 += bf_lo(q); a1 += bf_hi(q);
  }
  float oth0 = __shfl_xor(a0, 1);
  float oth1 = __shfl_xor(a1, 1);
  float A0 = j ? oth0 : a0;
  float A1v = j ? oth1 : a1;
  float A2v = j ? a0 : oth0;
  float di = dinv[n];
  uint2 xq = *(const uint2*)&xsb[(size_t)n * 2];
  float t0 = di * (A0 + bf_lo(xq.x));
  float t1 = di * (A1v + bf_hi(xq.x));
  float t2 = di * (A2v + bf_lo(xq.y));
  unsigned w0 = 0, w1 = 0;
#pragma unroll
  for (int q8 = 0; q8 < 4; ++q8) {
    int f = 8 * j + 2 * q8;
    float v0 = t0 * W1[f]     + t1 * W1[16 + f]     + t2 * W1[32 + f]     + b1[f];
    float v1 = t0 * W1[f + 1] + t1 * W1[16 + f + 1] + t2 * W1[32 + f + 1] + b1[f + 1];
    unsigned pb = f2e4m3(di * fmaxf(v0, 0.0f)) | (f2e4m3(di * fmaxf(v1, 0.0f)) << 8);
    if (q8 < 2) w0 |= pb << (16 * q8); else w1 |= pb << (16 * (q8 - 2));
  }
  *(uint2*)&ub[(size_t)n * 4 + j * 2] = make_uint2(w0, w1);
}

// ---- layer 2 gather: 4 lanes/node, LDS-LUT fp8 decode, self-loop u folded in ----
__global__ void k_gather2(const int* __restrict__ ssrc, const int* __restrict__ offs,
                          const unsigned* __restrict__ ub, float* __restrict__ A2) {
  __shared__ float lut[128];
  if (threadIdx.x < 128) lut[threadIdx.x] = e4m3f(threadIdx.x);
  __syncthreads();
  unsigned t = blockIdx.x * blockDim.x + threadIdx.x;
  unsigned n = t >> 2;
  int j = t & 3;
  if (n >= (unsigned)N_NODES) return;
  int o0 = offs[n], o1 = offs[n + 1];
  unsigned qs = ub[(size_t)n * 4 + j];                  // self-loop u[n] as acc init
  float a0 = lut[qs & 0x7F];
  float a1 = lut[(qs >> 8) & 0x7F];
  float a2 = lut[(qs >> 16) & 0x7F];
  float a3 = lut[(qs >> 24) & 0x7F];
  int i = o0;
  for (; i + 1 < o1; i += 2) {
    int s0 = ssrc[i], s1 = ssrc[i + 1];
    unsigned q0 = ub[(size_t)s0 * 4 + j];
    unsigned q1 = ub[(size_t)s1 * 4 + j];
    a0 += lut[q0 & 0x7F]         + lut[q1 & 0x7F];
    a1 += lut[(q0 >> 8) & 0x7F]  + lut[(q1 >> 8) & 0x7F];
    a2 += lut[(q0 >> 16) & 0x7F] + lut[(q1 >> 16) & 0x7F];
    a3 += lut[(q0 >> 24) & 0x7F] + lut[(q1 >> 24) & 0x7F];
  }
  if (i < o1) {
    unsigned q = ub[(size_t)ssrc[i] * 4 + j];
    a0 += lut[q & 0x7F];
    a1 += lut[(q >> 8) & 0x7F];
    a2 += lut[(q >> 16) & 0x7F];
    a3 += lut[(q >> 24) & 0x7F];
  }
  *(float4*)&A2[(size_t)n * 16 + j * 4] = make_float4(a0, a1, a2, a3);
}

// ---- pool v3: A2 already includes self-loop u; no fp8 decode, di factored out ----
__global__ void k_pool2(const float* __restrict__ A2,
                        const float* __restrict__ W2, const float* __restrict__ b2,
                        const float* __restrict__ dinv, const int* __restrict__ batch,
                        float* __restrict__ sums) {
  int f = threadIdx.x & 31, sub = threadIdx.x >> 5;
  int n0 = blockIdx.x * 128 + sub * 16;
  int n1 = min(n0 + 16, N_NODES);
  if (n0 >= n1) return;
  float w2col[16];
#pragma unroll
  for (int k = 0; k < 16; ++k) w2col[k] = W2[k * 32 + f];
  float bf = b2[f];
  int cur = batch[n0];
  float acc = 0.0f;
  for (int n = n0; n < n1; ++n) {
    int g = batch[n];
    if (g != cur) { atomicAdd(&sums[(size_t)cur * 32 + f], acc); acc = 0.0f; cur = g; }
    const float4* a2p = (const float4*)(A2 + (size_t)n * 16);
    float4 aa0 = a2p[0], aa1 = a2p[1], aa2 = a2p[2], aa3 = a2p[3];
    float v = aa0.x * w2col[0]  + aa0.y * w2col[1]  + aa0.z * w2col[2]  + aa0.w * w2col[3]
            + aa1.x * w2col[4]  + aa1.y * w2col[5]  + aa1.z * w2col[6]  + aa1.w * w2col[7]
            + aa2.x * w2col[8]  + aa2.y * w2col[9]  + aa2.z * w2col[10] + aa2.w * w2col[11]
            + aa3.x * w2col[12] + aa3.y * w2col[13] + aa3.z * w2col[14] + aa3.w * w2col[15];
    v = dinv[n] * v + bf;
    acc += fmaxf(v, 0.0f);
  }
  atomicAdd(&sums[(size_t)cur * 32 + f], acc);
}

// ---- final MLP + log_softmax, with FUSED segment bounds (binary search) ----
__global__ void k_mlp(const float* __restrict__ sums, const int* __restrict__ batch,
                      const float* __restrict__ fW1, const float* __restrict__ fb1,
                      const float* __restrict__ fW2, const float* __restrict__ fb2,
                      float* __restrict__ out) {
  __shared__ float w1s[32 * 64];
  __shared__ float w2s[64 * 3];
  __shared__ float b1s[64];
  __shared__ float b2s[3];
  for (int i = threadIdx.x; i < 32 * 64; i += blockDim.x) w1s[i] = fW1[i];
  for (int i = threadIdx.x; i < 64 * 3; i += blockDim.x) w2s[i] = fW2[i];
  for (int i = threadIdx.x; i < 64; i += blockDim.x) b1s[i] = fb1[i];
  for (int i = threadIdx.x; i < 3; i += blockDim.x) b2s[i] = fb2[i];
  __syncthreads();
  int g = blockIdx.x * blockDim.x + threadIdx.x;
  if (g >= NUM_GRAPHS) return;
  int lo = 0, hi = N_NODES;
  while (lo < hi) { int mid = (lo + hi) >> 1; if (batch[mid] < g) lo = mid + 1; else hi = mid; }
  int s0 = lo;
  int lo2 = s0, hi2 = N_NODES;
  while (lo2 < hi2) { int mid = (lo2 + hi2) >> 1; if (batch[mid] < g + 1) lo2 = mid + 1; else hi2 = mid; }
  float c = fmaxf((float)(lo2 - s0), 1.0f);
  float p[32];
#pragma unroll
  for (int i = 0; i < 32; ++i) p[i] = sums[(size_t)g * 32 + i] / c;
  float z2[3] = {b2s[0], b2s[1], b2s[2]};
  for (int j = 0; j < 64; ++j) {
    float a = b1s[j];
#pragma unroll
    for (int i = 0; i < 32; ++i) a += p[i] * w1s[i * 64 + j];
    a = fmaxf(a, 0.0f);
#pragma unroll
    for (int k = 0; k < 3; ++k) z2[k] += a * w2s[j * 3 + k];
  }
  float m = fmaxf(fmaxf(z2[0], z2[1]), z2[2]);
  float l = logf(expf(z2[0] - m) + expf(z2[1] - m) + expf(z2[2] - m));
#pragma unroll
  for (int k = 0; k < 3; ++k) out[(size_t)g * 3 + k] = z2[k] - m - l;
}

extern "C" void kernel_launch(void* const* d_in, const int* in_sizes, int n_in,
                              void* d_out, int out_size, void* d_ws, size_t ws_size,
                              hipStream_t stream) {
  const float* x     = (const float*)d_in[0];
  const int*   ei    = (const int*)d_in[1];   // [2, E]
  const int*   batch = (const int*)d_in[2];
  const float* W1    = (const float*)d_in[3];
  const float* b1    = (const float*)d_in[4];
  const float* W2    = (const float*)d_in[5];
  const float* b2    = (const float*)d_in[6];
  const float* fW1   = (const float*)d_in[7];
  const float* fb1   = (const float*)d_in[8];
  const float* fW2   = (const float*)d_in[9];
  const float* fb2   = (const float*)d_in[10];
  const int* src = ei;
  const int* dst = ei + N_EDGES;

  // ---- workspace layout (≈95 MB) ----
  float* ws       = (float*)d_ws;
  float* dinv     = ws;                           // 524,288 f
  unsigned* xsb   = (unsigned*)(dinv + 524288);   // 1,048,576 u32 (2/node)
  unsigned* ub    = xsb + 1048576;                // 4,194,304 u32 slot (fp8: 4/node used)
  float* scratch  = (float*)(ub + 4194304);       // 2,000,000 f (scan scratch)
  float* sums     = scratch + 2000000;            // 16384
  int* offs       = (int*)(sums + 16384);         // 524,288 (N_NODES+1 used)
  int* ssrc       = offs + 524288;                // 8,000,000
  int* pairs      = ssrc + 8000000;               // 8,000,000
  // aliases (dead ranges reused):
  int* H    = (int*)scratch;                      // NH = 477,753
  int* Sarr = H + NH;                             // 477,753
  int* bsum = Sarr + NH;                          // 1867  (total 957,373 < 2,000,000)
  float* A2 = (float*)pairs;                      // pairs dead after k_csr

  hipMemsetAsync(sums, 0, (size_t)NUM_GRAPHS * 32 * 4, stream);

  const int B = 256;
  k_hist<<<NBLK_A, B, 0, stream>>>(dst, H);
  k_scan1<<<NSB, SCAN_B, 0, stream>>>(H, Sarr, bsum, NH);
  k_scan2<<<1, SCAN_B, 0, stream>>>(bsum, NSB);
  k_scatter_bkt<<<NBLK_A, 512, 0, stream>>>(src, dst, H, Sarr, bsum, pairs);
  k_csr<<<NBKT, 1024, 0, stream>>>(pairs, Sarr, bsum, x, ssrc, offs, dinv, xsb);
  k_g1f1<<<((size_t)N_NODES * 2 + B - 1) / B, B, 0, stream>>>(ssrc, offs, xsb, dinv, W1, b1, ub);
  k_gather2<<<((size_t)N_NODES * 4 + B - 1) / B, B, 0, stream>>>(ssrc, offs, ub, A2);
  k_pool2<<<(N_NODES + 127) / 128, B, 0, stream>>>(A2, W2, b2, dinv, batch, sums);
  k_mlp<<<(NUM_GRAPHS + B - 1) / B, B, 0, stream>>>(sums, batch, fW1, fb1, fW2, fb2, (float*)d_out);
}